// Round 11
// baseline (53.589 us; speedup 1.0000x reference)
//
#include <hip/hip_runtime.h>

#define EPSF 1e-20f

constexpr int Hh = 768, Ww = 768, Bb = 4;
constexpr int PLANE = Hh * Ww;
constexpr int TSX = 32, TSY = 16;       // output tile (w x h)
constexpr int R3Y = TSY + 6, R3X = TSX + 6;   // 22 x 38 halo-3 (dq, c)
constexpr int R2Y = TSY + 4, R2X = TSX + 4;   // 20 x 36 halo-2 (tc, ts)
constexpr int R1Y = TSY + 2, R1X = TSX + 2;   // 18 x 34 halo-1 (s)

// fused: stage 1 (hierarchical argmax) + stage 2 (conv) + stage 3; 16-row tiles
__global__ __launch_bounds__(256)
void fused_all(const float* __restrict__ x, const float* __restrict__ scs,
               const float* __restrict__ cs,
               const float* __restrict__ w_sp_d, const float* __restrict__ w_sp_s,
               const float* __restrict__ w_pow_s, const float* __restrict__ w_prop_s,
               float* __restrict__ out) {
    __shared__ float2 s_qc[R3Y][R3X];   // (.x = dq = d/(c+eps), .y = c)
    __shared__ float2 s_t[R2Y][R2X];    // (tc, ts)
    __shared__ float  s_s[R1Y][R1X];    // s, 0 outside image
    __shared__ float  sw[20];           // wd[0..8], ws[9..17], wps, wpow
    __shared__ float  swraw[18];        // unnormalized softplus values

    // XCD-bijective swizzle: 4608 blocks = 8 XCDs x 576 (contiguous half-batch
    // per XCD -> halo re-reads hit the XCD-private L2).
    const int orig = blockIdx.x;
    const int swz  = (orig & 7) * 576 + (orig >> 3);
    const int b    = swz / 1152;
    const int rem  = swz - b * 1152;
    const int ty0  = (rem / 24) * TSY;
    const int tx0  = (rem % 24) * TSX;

    const int tid = threadIdx.x;
    const float* dcd = x + b * PLANE;
    const float* cd  = x + (Bb + b) * PLANE;

    // ---- parallel weight prep (lanes 0..10 of wave 0; wave-lockstep safe) ----
    if (tid < 9) {
        int r = tid / 3, c = tid - r * 3;
        int cc = (c == 2) ? 0 : c;              // mirrored 3rd column
        swraw[tid]     = log1pf(expf(w_sp_d[r * 2 + cc]));
        swraw[9 + tid] = log1pf(expf(w_sp_s[r * 2 + cc]));
    }
    if (tid == 9)  sw[18] = 1.f / (1.f + expf(-w_prop_s[0]));   // wps
    if (tid == 10) sw[19] = log1pf(expf(w_pow_s[0]));           // wpow
    if (tid < 9) {   // same-wave: raw writes complete (lockstep) before reads
        float sum_d = 0.f, sum_s = 0.f;
        #pragma unroll
        for (int k = 0; k < 9; ++k) { sum_d += swraw[k]; sum_s += swraw[9 + k]; }
        sw[tid]     = swraw[tid]     / sum_d;
        sw[9 + tid] = swraw[9 + tid] / sum_s;
    }

    // ---- Phase A: vectorized load at halo-3 (22 rows x 10 float4 segs) ----
    if (tid < R3Y * 10) {   // 220 items, one per thread
        int row = tid / 10, seg = tid - row * 10;
        int gy = ty0 - 3 + row;
        int gxb = tx0 - 4 + seg * 4;
        float4 vd4 = make_float4(0.f, 0.f, 0.f, 0.f);
        float4 vc4 = vd4;
        if ((unsigned)gy < (unsigned)Hh) {
            bool safe = (seg > 0 && seg < 9) || (seg == 0 ? (tx0 > 0) : (tx0 + TSX < Ww));
            if (safe) {
                vd4 = *(const float4*)(dcd + gy * Ww + gxb);
                vc4 = *(const float4*)(cd  + gy * Ww + gxb);
            } else {
                if ((unsigned)(gxb + 0) < (unsigned)Ww) { vd4.x = dcd[gy*Ww+gxb+0]; vc4.x = cd[gy*Ww+gxb+0]; }
                if ((unsigned)(gxb + 1) < (unsigned)Ww) { vd4.y = dcd[gy*Ww+gxb+1]; vc4.y = cd[gy*Ww+gxb+1]; }
                if ((unsigned)(gxb + 2) < (unsigned)Ww) { vd4.z = dcd[gy*Ww+gxb+2]; vc4.z = cd[gy*Ww+gxb+2]; }
                if ((unsigned)(gxb + 3) < (unsigned)Ww) { vd4.w = dcd[gy*Ww+gxb+3]; vc4.w = cd[gy*Ww+gxb+3]; }
            }
        }
        int lxb = seg * 4 - 1;   // lx of component 0
        if ((unsigned)(lxb + 0) < (unsigned)R3X) s_qc[row][lxb + 0] = make_float2(vd4.x / (vc4.x + EPSF), vc4.x);
        if ((unsigned)(lxb + 1) < (unsigned)R3X) s_qc[row][lxb + 1] = make_float2(vd4.y / (vc4.y + EPSF), vc4.y);
        if ((unsigned)(lxb + 2) < (unsigned)R3X) s_qc[row][lxb + 2] = make_float2(vd4.z / (vc4.z + EPSF), vc4.z);
        if ((unsigned)(lxb + 3) < (unsigned)R3X) s_qc[row][lxb + 3] = make_float2(vd4.w / (vc4.w + EPSF), vc4.w);
    }

    // ---- Prefetch cs/scs for Phase B (36 cols x 7 groups of 3 rows) ----
    const int xB = tid % R2X;          // 0..35
    const int tyB = tid / R2X;         // active < 7 (252 threads)
    const int yb0 = tyB * 3;
    float pcs[3], pscs[3];
    if (tyB < 7) {
        int gx = tx0 - 2 + xB;
        bool colok = (unsigned)gx < (unsigned)Ww;
        #pragma unroll
        for (int j = 0; j < 3; ++j) {
            int yb = yb0 + j;
            int gy = ty0 - 2 + yb;
            bool ok = (yb < R2Y) && colok && (unsigned)gy < (unsigned)Hh;
            int idx = ok ? (b * PLANE + gy * Ww + gx) : 0;
            pcs[j]  = ok ? cs[idx]  : 0.f;
            pscs[j] = ok ? scs[idx] : 0.f;
        }
    }
    __syncthreads();

    const float wps  = sw[18];
    const float wpow = sw[19];
    const float onemw = 1.f - wps;

    // ---- Phase B: stage 1, column sweep. Hierarchical first-wins argmax:
    // row-max over dx (k-minor) then combine over dy (k-major) — exactly
    // reproduces jnp.argmax first-occurrence order.
    if (tyB < 7) {
        float ma[3], md[3], mc[3];    // jmax row-partials (key, dq, c)
        float nv[3], nq[3];           // jmin row-partials (vc, dq+eps)
#define HROW_B(rr, slot) { \
        float2 q0 = s_qc[rr][xB]; float2 q1 = s_qc[rr][xB + 1]; float2 q2 = s_qc[rr][xB + 2]; \
        float a0 = q0.x * q0.y, a1 = q1.x * q1.y, a2 = q2.x * q2.y; \
        float A = a0, D = q0.x, C = q0.y; \
        if (a1 > A) { A = a1; D = q1.x; C = q1.y; } \
        if (a2 > A) { A = a2; D = q2.x; C = q2.y; } \
        ma[slot] = A; md[slot] = D; mc[slot] = C; \
        float V = q0.y, Q = q0.x + EPSF; \
        float e1 = q1.x + EPSF, e2 = q2.x + EPSF; \
        if (q1.y * Q > V * e1) { V = q1.y; Q = e1; } \
        if (q2.y * Q > V * e2) { V = q2.y; Q = e2; } \
        nv[slot] = V; nq[slot] = Q; }
        HROW_B(yb0 + 0, 0)
        HROW_B(yb0 + 1, 1)
        #pragma unroll
        for (int j = 0; j < 3; ++j) {
            const int yb = yb0 + j;
            if (yb < R2Y) {
                const int sl2 = (j + 2) % 3, s0 = j % 3, s1 = (j + 1) % 3;
                HROW_B(yb + 2, sl2)
                float A = ma[s0], D = md[s0], C = mc[s0];
                if (ma[s1]  > A) { A = ma[s1];  D = md[s1];  C = mc[s1];  }
                if (ma[sl2] > A) { A = ma[sl2]; D = md[sl2]; C = mc[sl2]; }
                float V = nv[s0], Q = nq[s0];
                if (nv[s1]  * Q > V * nq[s1])  { V = nv[s1];  Q = nq[s1];  }
                if (nv[sl2] * Q > V * nq[sl2]) { V = nv[sl2]; Q = nq[sl2]; }
                const int gy = ty0 - 2 + yb, gx = tx0 - 2 + xB;
                float tc = 0.f, ts = 0.f;
                if ((unsigned)gy < (unsigned)Hh && (unsigned)gx < (unsigned)Ww) {
                    float s_new = __builtin_amdgcn_exp2f(wpow *
                        (__builtin_amdgcn_logf(Q) - __builtin_amdgcn_logf(D + EPSF)));
                    float cs_new = C * V;
                    tc = pcs[j]  * wps + cs_new * onemw;
                    ts = pscs[j] * wps + s_new * cs_new * onemw;
                }
                s_t[yb][xB] = make_float2(tc, ts);
            }
        }
    }
    __syncthreads();

    // ---- Phase C(a): interior conv, 16 rows x 16 groups of 2 px ----
    // Interior px (rC, c2+j) = halo-1 coord (rC+1, c2+1+j); taps are
    // s_t[rC+1+r][c2+1+j+kx] -> row base rC+1, col window c2+1..c2+4.
    {
        const int rC = tid >> 4;            // interior row 0..15
        const int c2 = (tid & 15) * 2;      // interior col base 0,2,..,30
        float aC0 = 0.f, aS0 = 0.f, aC1 = 0.f, aS1 = 0.f;
        #pragma unroll
        for (int r = 0; r < 3; ++r) {
            const float wa = sw[9 + 3 * r];
            const float wb = sw[9 + 3 * r + 1];
            float2 t0 = s_t[rC + 1 + r][c2 + 1];
            float2 t1 = s_t[rC + 1 + r][c2 + 2];
            float2 t2 = s_t[rC + 1 + r][c2 + 3];
            float2 t3 = s_t[rC + 1 + r][c2 + 4];
            aC0 += wa * (t0.x + t2.x) + wb * t1.x;
            aS0 += wa * (t0.y + t2.y) + wb * t1.y;
            aC1 += wa * (t1.x + t3.x) + wb * t2.x;
            aS1 += wa * (t1.y + t3.y) + wb * t2.y;
        }
        s_s[rC + 1][c2 + 1] = aS0 * __builtin_amdgcn_rcpf(aC0 + EPSF);
        s_s[rC + 1][c2 + 2] = aS1 * __builtin_amdgcn_rcpf(aC1 + EPSF);
        int idx = (ty0 + rC) * Ww + (tx0 + c2);
        *(float2*)(out + (8 + b)  * PLANE + idx) = make_float2(aS0, aS1);
        *(float2*)(out + (12 + b) * PLANE + idx) = make_float2(aC0, aC1);
    }
    // ---- Phase C(b): halo-1 ring (100 px), direct 9-tap; s=0 outside image
    if (tid < 100) {
        int yc, xC;
        if (tid < 34)       { yc = 0;  xC = tid; }
        else if (tid < 68)  { yc = R1Y - 1; xC = tid - 34; }
        else if (tid < 84)  { yc = 1 + (tid - 68); xC = 0; }
        else                { yc = 1 + (tid - 84); xC = R1X - 1; }
        float aC = 0.f, aS = 0.f;
        #pragma unroll
        for (int k = 0; k < 9; ++k) {
            float2 t = s_t[yc + k / 3][xC + k % 3];
            aC += sw[9 + k] * t.x;
            aS += sw[9 + k] * t.y;
        }
        int gy = ty0 - 1 + yc, gx = tx0 - 1 + xC;
        bool in_img = (unsigned)gy < (unsigned)Hh && (unsigned)gx < (unsigned)Ww;
        s_s[yc][xC] = in_img ? (aS * __builtin_amdgcn_rcpf(aC + EPSF)) : 0.f;
    }
    __syncthreads();

    // ---- Phase D: stage 3, column sweep (32 cols x 8 groups of 2 rows) ----
    {
        const int xD = tid & 31, tyD = tid >> 5;
        const int yd0 = tyD * 2;
        float wdk[9];
        #pragma unroll
        for (int k = 0; k < 9; ++k) wdk[k] = sw[k];
        float  srw[3][3];
        float2 qrw[3][3];
#define HROW_D(rr, slot) { \
        srw[slot][0] = s_s[rr][xD]; srw[slot][1] = s_s[rr][xD + 1]; srw[slot][2] = s_s[rr][xD + 2]; \
        qrw[slot][0] = s_qc[rr + 2][xD + 2]; qrw[slot][1] = s_qc[rr + 2][xD + 3]; qrw[slot][2] = s_qc[rr + 2][xD + 4]; }
        HROW_D(yd0 + 0, 0)
        HROW_D(yd0 + 1, 1)
#define TAP_D(slot, kk, cc2) { \
        float wsk = ((kk) == 4) ? 1.f : (srw[slot][cc2] * sc); \
        float w = wdk[kk] * wsk; \
        float2 q = qrw[slot][cc2]; \
        acc_d += w * (q.x * (q.y + EPSF)); \
        acc_c += w * q.y; \
        acc_w += w; }
        #pragma unroll
        for (int j = 0; j < 2; ++j) {
            const int sl2 = (j + 2) % 3, s0 = j % 3, s1 = (j + 1) % 3;
            HROW_D(yd0 + j + 2, sl2)
            float sc = srw[s1][1];
            float acc_d = 0.f, acc_c = 0.f, acc_w = 0.f;
            TAP_D(s0, 0, 0) TAP_D(s0, 1, 1) TAP_D(s0, 2, 2)
            TAP_D(s1, 3, 0) TAP_D(s1, 4, 1) TAP_D(s1, 5, 2)
            TAP_D(sl2, 6, 0) TAP_D(sl2, 7, 1) TAP_D(sl2, 8, 2)
            float rinv = __builtin_amdgcn_rcpf(acc_w + EPSF);
            const int iy = yd0 + j;
            int idx = (ty0 + iy) * Ww + (tx0 + xD);
            out[(2 * b)     * PLANE + idx] = acc_d * rinv;   // x_out d-part
            out[(2 * b + 1) * PLANE + idx] = acc_c * rinv;   // x_out c-part
        }
    }
}

extern "C" void kernel_launch(void* const* d_in, const int* in_sizes, int n_in,
                              void* d_out, int out_size, void* d_ws, size_t ws_size,
                              hipStream_t stream) {
    const float* x        = (const float*)d_in[0];
    const float* scs      = (const float*)d_in[1];
    const float* cs       = (const float*)d_in[2];
    // d_in[3] = w_channel_d (1,1) -> normalizes to 1, unused
    const float* w_sp_d   = (const float*)d_in[4];
    const float* w_pow_s  = (const float*)d_in[5];
    const float* w_prop_s = (const float*)d_in[6];
    // d_in[7] = w_channel_s (1,1) -> normalizes to 1, unused
    const float* w_sp_s   = (const float*)d_in[8];
    float* out  = (float*)d_out;

    fused_all<<<dim3(24 * 48 * Bb), 256, 0, stream>>>(x, scs, cs, w_sp_d, w_sp_s,
                                                      w_pow_s, w_prop_s, out);
}

// Round 12
// 31.059 us; speedup vs baseline: 1.7254x; 1.7254x over previous
//
#include <hip/hip_runtime.h>

#define EPSF 1e-20f

constexpr int Hh = 768, Ww = 768, Bb = 4;
constexpr int PLANE = Hh * Ww;
constexpr int TSX = 32, TSY = 24;             // output tile (w x h)
constexpr int R3Y = TSY + 6, R3X = TSX + 6;   // 30 x 38 halo-3 (dq, c)
constexpr int R2Y = TSY + 4, R2X = TSX + 4;   // 28 x 36 halo-2 (tc, ts)
constexpr int R1Y = TSY + 2, R1X = TSX + 2;   // 26 x 34 halo-1 (s)

// fused: stage 1 (hierarchical argmax) + stage 2 (conv) + stage 3
// Structure = round-7 proven (column sweeps + C2 staging + aligned D writes),
// with 24-row tiles (12 blocks/CU, 7 resident) and parallel weight prep.
__global__ __launch_bounds__(256)
void fused_all(const float* __restrict__ x, const float* __restrict__ scs,
               const float* __restrict__ cs,
               const float* __restrict__ w_sp_d, const float* __restrict__ w_sp_s,
               const float* __restrict__ w_pow_s, const float* __restrict__ w_prop_s,
               float* __restrict__ out) {
    __shared__ float2 s_qc[R3Y][R3X];   // (.x = dq = d/(c+eps), .y = c)  9120B
    __shared__ float2 s_t[R2Y][R2X];    // B: (tc,ts); C2+: (accC,accS)   8064B
    __shared__ float  s_s[R1Y][R1X];    // s, 0 outside image             3536B
    __shared__ float  sw[20];           // wd[0..8], ws[9..17], wps, wpow
    __shared__ float  swraw[18];        // unnormalized softplus values

    // XCD-bijective swizzle: 3072 blocks = 8 XCDs x 384 (half a batch each,
    // contiguous -> halo re-reads hit the XCD-private L2).
    const int orig = blockIdx.x;
    const int swz  = (orig & 7) * 384 + (orig >> 3);
    const int b    = swz / 768;
    const int rem  = swz - b * 768;
    const int ty0  = (rem / 24) * TSY;
    const int tx0  = (rem % 24) * TSX;

    const int tid = threadIdx.x;
    const float* dcd = x + b * PLANE;
    const float* cd  = x + (Bb + b) * PLANE;

    // ---- parallel weight prep (lanes 0..10 of wave 0; wave-lockstep safe) ----
    if (tid < 9) {
        int r = tid / 3, c = tid - r * 3;
        int cc = (c == 2) ? 0 : c;              // mirrored 3rd column
        swraw[tid]     = log1pf(expf(w_sp_d[r * 2 + cc]));
        swraw[9 + tid] = log1pf(expf(w_sp_s[r * 2 + cc]));
    }
    if (tid == 9)  sw[18] = 1.f / (1.f + expf(-w_prop_s[0]));   // wps
    if (tid == 10) sw[19] = log1pf(expf(w_pow_s[0]));           // wpow
    if (tid < 9) {   // same-wave: raw writes complete (lockstep) before reads
        float sum_d = 0.f, sum_s = 0.f;
        #pragma unroll
        for (int k = 0; k < 9; ++k) { sum_d += swraw[k]; sum_s += swraw[9 + k]; }
        sw[tid]     = swraw[tid]     / sum_d;
        sw[9 + tid] = swraw[9 + tid] / sum_s;
    }

    // ---- Phase A: vectorized load at halo-3 (30 rows x 10 float4 segs) ----
    for (int it = tid; it < R3Y * 10; it += 256) {   // 300 items
        int row = it / 10, seg = it - row * 10;
        int gy = ty0 - 3 + row;
        int gxb = tx0 - 4 + seg * 4;
        float4 vd4 = make_float4(0.f, 0.f, 0.f, 0.f);
        float4 vc4 = vd4;
        if ((unsigned)gy < (unsigned)Hh) {
            bool safe = (seg > 0 && seg < 9) || (seg == 0 ? (tx0 > 0) : (tx0 + TSX < Ww));
            if (safe) {
                vd4 = *(const float4*)(dcd + gy * Ww + gxb);
                vc4 = *(const float4*)(cd  + gy * Ww + gxb);
            } else {
                if ((unsigned)(gxb + 0) < (unsigned)Ww) { vd4.x = dcd[gy*Ww+gxb+0]; vc4.x = cd[gy*Ww+gxb+0]; }
                if ((unsigned)(gxb + 1) < (unsigned)Ww) { vd4.y = dcd[gy*Ww+gxb+1]; vc4.y = cd[gy*Ww+gxb+1]; }
                if ((unsigned)(gxb + 2) < (unsigned)Ww) { vd4.z = dcd[gy*Ww+gxb+2]; vc4.z = cd[gy*Ww+gxb+2]; }
                if ((unsigned)(gxb + 3) < (unsigned)Ww) { vd4.w = dcd[gy*Ww+gxb+3]; vc4.w = cd[gy*Ww+gxb+3]; }
            }
        }
        int lxb = seg * 4 - 1;   // lx of component 0
        if ((unsigned)(lxb + 0) < (unsigned)R3X) s_qc[row][lxb + 0] = make_float2(vd4.x / (vc4.x + EPSF), vc4.x);
        if ((unsigned)(lxb + 1) < (unsigned)R3X) s_qc[row][lxb + 1] = make_float2(vd4.y / (vc4.y + EPSF), vc4.y);
        if ((unsigned)(lxb + 2) < (unsigned)R3X) s_qc[row][lxb + 2] = make_float2(vd4.z / (vc4.z + EPSF), vc4.z);
        if ((unsigned)(lxb + 3) < (unsigned)R3X) s_qc[row][lxb + 3] = make_float2(vd4.w / (vc4.w + EPSF), vc4.w);
    }

    // ---- Prefetch cs/scs for Phase B (36 cols x 7 groups of 4 rows) ----
    const int xB = tid % R2X;          // 0..35
    const int tyB = tid / R2X;         // active < 7 (252 threads)
    const int yb0 = tyB * 4;
    float pcs[4], pscs[4];
    if (tyB < 7) {
        int gx = tx0 - 2 + xB;
        bool colok = (unsigned)gx < (unsigned)Ww;
        #pragma unroll
        for (int j = 0; j < 4; ++j) {
            int gy = ty0 - 2 + yb0 + j;
            bool ok = colok && (unsigned)gy < (unsigned)Hh;
            int idx = ok ? (b * PLANE + gy * Ww + gx) : 0;
            pcs[j]  = ok ? cs[idx]  : 0.f;
            pscs[j] = ok ? scs[idx] : 0.f;
        }
    }
    __syncthreads();

    const float wps  = sw[18];
    const float wpow = sw[19];
    const float onemw = 1.f - wps;

    // ---- Phase B: stage 1, column sweep. Hierarchical first-wins argmax:
    // row-max over dx (k-minor) then combine over dy (k-major) — exactly
    // reproduces jnp.argmax first-occurrence order.
    if (tyB < 7) {
        float ma[3], md[3], mc[3];    // jmax row-partials (key, dq, c)
        float nv[3], nq[3];           // jmin row-partials (vc, dq+eps)
#define HROW_B(rr, slot) { \
        float2 q0 = s_qc[rr][xB]; float2 q1 = s_qc[rr][xB + 1]; float2 q2 = s_qc[rr][xB + 2]; \
        float a0 = q0.x * q0.y, a1 = q1.x * q1.y, a2 = q2.x * q2.y; \
        float A = a0, D = q0.x, C = q0.y; \
        if (a1 > A) { A = a1; D = q1.x; C = q1.y; } \
        if (a2 > A) { A = a2; D = q2.x; C = q2.y; } \
        ma[slot] = A; md[slot] = D; mc[slot] = C; \
        float V = q0.y, Q = q0.x + EPSF; \
        float e1 = q1.x + EPSF, e2 = q2.x + EPSF; \
        if (q1.y * Q > V * e1) { V = q1.y; Q = e1; } \
        if (q2.y * Q > V * e2) { V = q2.y; Q = e2; } \
        nv[slot] = V; nq[slot] = Q; }
        HROW_B(yb0 + 0, 0)
        HROW_B(yb0 + 1, 1)
        #pragma unroll
        for (int j = 0; j < 4; ++j) {
            const int sl2 = (j + 2) % 3, s0 = j % 3, s1 = (j + 1) % 3;
            HROW_B(yb0 + j + 2, sl2)
            float A = ma[s0], D = md[s0], C = mc[s0];
            if (ma[s1]  > A) { A = ma[s1];  D = md[s1];  C = mc[s1];  }
            if (ma[sl2] > A) { A = ma[sl2]; D = md[sl2]; C = mc[sl2]; }
            float V = nv[s0], Q = nq[s0];
            if (nv[s1]  * Q > V * nq[s1])  { V = nv[s1];  Q = nq[s1];  }
            if (nv[sl2] * Q > V * nq[sl2]) { V = nv[sl2]; Q = nq[sl2]; }
            const int yb = yb0 + j;
            const int gy = ty0 - 2 + yb, gx = tx0 - 2 + xB;
            float tc = 0.f, ts = 0.f;
            if ((unsigned)gy < (unsigned)Hh && (unsigned)gx < (unsigned)Ww) {
                float s_new = __builtin_amdgcn_exp2f(wpow *
                    (__builtin_amdgcn_logf(Q) - __builtin_amdgcn_logf(D + EPSF)));
                float cs_new = C * V;
                tc = pcs[j]  * wps + cs_new * onemw;
                ts = pscs[j] * wps + s_new * cs_new * onemw;
            }
            s_t[yb][xB] = make_float2(tc, ts);
        }
    }
    __syncthreads();

    // ---- Phase C: stage 2 conv, column sweep (34 cols x 7 groups of 4) ----
    // Results kept in registers; re-staged into dead s_t for aligned D writes.
    const int xC = tid % R1X;          // 0..33
    const int tyC = tid / R1X;         // active < 7 (238 threads)
    const int yc0 = tyC * 4;
    float2 cres[4];
    if (tyC < 7) {
        const float wa0 = sw[9],  wb0 = sw[10];
        const float wa1 = sw[12], wb1 = sw[13];
        const float wa2 = sw[15], wb2 = sw[16];
        float2 u[3], tm[3];
#define HROW_C(rr, slot) { \
        float2 t0 = s_t[rr][xC]; float2 t1 = s_t[rr][xC + 1]; float2 t2 = s_t[rr][xC + 2]; \
        u[slot] = make_float2(t0.x + t2.x, t0.y + t2.y); tm[slot] = t1; }
        HROW_C(yc0 + 0, 0)
        HROW_C(yc0 + 1, 1)
        #pragma unroll
        for (int j = 0; j < 4; ++j) {
            const int yc = yc0 + j;
            if (yc < R1Y) {
                const int sl2 = (j + 2) % 3, s0 = j % 3, s1 = (j + 1) % 3;
                HROW_C(yc + 2, sl2)
                float accC = wa0 * u[s0].x + wb0 * tm[s0].x
                           + wa1 * u[s1].x + wb1 * tm[s1].x
                           + wa2 * u[sl2].x + wb2 * tm[sl2].x;
                float accS = wa0 * u[s0].y + wb0 * tm[s0].y
                           + wa1 * u[s1].y + wb1 * tm[s1].y
                           + wa2 * u[sl2].y + wb2 * tm[sl2].y;
                const int gy = ty0 - 1 + yc, gx = tx0 - 1 + xC;
                bool in_img = (unsigned)gy < (unsigned)Hh && (unsigned)gx < (unsigned)Ww;
                s_s[yc][xC] = in_img ? (accS * __builtin_amdgcn_rcpf(accC + EPSF)) : 0.f;
                cres[j] = make_float2(accC, accS);
            }
        }
    }
    __syncthreads();   // all s_t reads done; s_s ready

    // ---- Phase C2: dump conv results into dead s_t for aligned writes ----
    if (tyC < 7) {
        #pragma unroll
        for (int j = 0; j < 4; ++j) {
            const int yc = yc0 + j;
            if (yc < R1Y) s_t[yc][xC] = cres[j];
        }
    }
    __syncthreads();

    // ---- Phase D: stage 3 + ALL global writes (32 cols x 8 groups of 3) ----
    {
        const int xD = tid & 31, tyD = tid >> 5;
        const int yd0 = tyD * 3;
        float wdk[9];
        #pragma unroll
        for (int k = 0; k < 9; ++k) wdk[k] = sw[k];
        float  srw[3][3];
        float2 qrw[3][3];
#define HROW_D(rr, slot) { \
        srw[slot][0] = s_s[rr][xD]; srw[slot][1] = s_s[rr][xD + 1]; srw[slot][2] = s_s[rr][xD + 2]; \
        qrw[slot][0] = s_qc[rr + 2][xD + 2]; qrw[slot][1] = s_qc[rr + 2][xD + 3]; qrw[slot][2] = s_qc[rr + 2][xD + 4]; }
        HROW_D(yd0 + 0, 0)
        HROW_D(yd0 + 1, 1)
#define TAP_D(slot, kk, cc2) { \
        float wsk = ((kk) == 4) ? 1.f : (srw[slot][cc2] * sc); \
        float w = wdk[kk] * wsk; \
        float2 q = qrw[slot][cc2]; \
        acc_d += w * (q.x * (q.y + EPSF)); \
        acc_c += w * q.y; \
        acc_w += w; }
        #pragma unroll
        for (int j = 0; j < 3; ++j) {
            const int sl2 = (j + 2) % 3, s0 = j % 3, s1 = (j + 1) % 3;
            HROW_D(yd0 + j + 2, sl2)
            float sc = srw[s1][1];
            float acc_d = 0.f, acc_c = 0.f, acc_w = 0.f;
            TAP_D(s0, 0, 0) TAP_D(s0, 1, 1) TAP_D(s0, 2, 2)
            TAP_D(s1, 3, 0) TAP_D(s1, 4, 1) TAP_D(s1, 5, 2)
            TAP_D(sl2, 6, 0) TAP_D(sl2, 7, 1) TAP_D(sl2, 8, 2)
            float rinv = __builtin_amdgcn_rcpf(acc_w + EPSF);
            const int iy = yd0 + j;
            int idx = (ty0 + iy) * Ww + (tx0 + xD);
            float2 cv = s_t[iy + 1][xD + 1];   // (accC, accS) for this pixel
            out[(2 * b)     * PLANE + idx] = acc_d * rinv;   // x_out d-part
            out[(2 * b + 1) * PLANE + idx] = acc_c * rinv;   // x_out c-part
            out[(8 + b)     * PLANE + idx] = cv.y;           // scs_out
            out[(12 + b)    * PLANE + idx] = cv.x;           // cs_out
        }
    }
}

extern "C" void kernel_launch(void* const* d_in, const int* in_sizes, int n_in,
                              void* d_out, int out_size, void* d_ws, size_t ws_size,
                              hipStream_t stream) {
    const float* x        = (const float*)d_in[0];
    const float* scs      = (const float*)d_in[1];
    const float* cs       = (const float*)d_in[2];
    // d_in[3] = w_channel_d (1,1) -> normalizes to 1, unused
    const float* w_sp_d   = (const float*)d_in[4];
    const float* w_pow_s  = (const float*)d_in[5];
    const float* w_prop_s = (const float*)d_in[6];
    // d_in[7] = w_channel_s (1,1) -> normalizes to 1, unused
    const float* w_sp_s   = (const float*)d_in[8];
    float* out  = (float*)d_out;

    fused_all<<<dim3(24 * 32 * Bb), 256, 0, stream>>>(x, scs, cs, w_sp_d, w_sp_s,
                                                      w_pow_s, w_prop_s, out);
}

// Round 13
// 30.496 us; speedup vs baseline: 1.7573x; 1.0185x over previous
//
#include <hip/hip_runtime.h>
#include <hip/hip_fp16.h>

#define EPSF 1e-20f

constexpr int Hh = 768, Ww = 768, Bb = 4;
constexpr int PLANE = Hh * Ww;
constexpr int TSX = 32, TSY = 24;             // output tile (w x h)
constexpr int R3Y = TSY + 6, R3X = TSX + 6;   // 30 x 38 halo-3 (dq, c)
constexpr int R2Y = TSY + 4, R2X = TSX + 4;   // 28 x 36 halo-2 (tc, ts)
constexpr int R1Y = TSY + 2, R1X = TSX + 2;   // 26 x 34 halo-1 (s)

// fused: stage 1 (hierarchical argmax) + stage 2 (conv) + stage 3
// r12 structure; s_s stored as half (s feeds only stage-3 weights, never an
// output) -> LDS 20872 -> 19104 B -> 8 resident blocks/CU (thread cap).
__global__ __launch_bounds__(256)
void fused_all(const float* __restrict__ x, const float* __restrict__ scs,
               const float* __restrict__ cs,
               const float* __restrict__ w_sp_d, const float* __restrict__ w_sp_s,
               const float* __restrict__ w_pow_s, const float* __restrict__ w_prop_s,
               float* __restrict__ out) {
    __shared__ float2 s_qc[R3Y][R3X];   // (.x = dq = d/(c+eps), .y = c)  9120B
    __shared__ float2 s_t[R2Y][R2X];    // B: (tc,ts); C2+: (accC,accS)   8064B
    __shared__ __half s_s[R1Y][R1X];    // s (half), 0 outside image      1768B
    __shared__ float  sw[20];           // wd[0..8], ws[9..17], wps, wpow
    __shared__ float  swraw[18];        // unnormalized softplus values

    // XCD-bijective swizzle: 3072 blocks = 8 XCDs x 384 (half a batch each,
    // contiguous -> halo re-reads hit the XCD-private L2).
    const int orig = blockIdx.x;
    const int swz  = (orig & 7) * 384 + (orig >> 3);
    const int b    = swz / 768;
    const int rem  = swz - b * 768;
    const int ty0  = (rem / 24) * TSY;
    const int tx0  = (rem % 24) * TSX;

    const int tid = threadIdx.x;
    const float* dcd = x + b * PLANE;
    const float* cd  = x + (Bb + b) * PLANE;

    // ---- parallel weight prep (lanes 0..10 of wave 0; wave-lockstep safe) ----
    if (tid < 9) {
        int r = tid / 3, c = tid - r * 3;
        int cc = (c == 2) ? 0 : c;              // mirrored 3rd column
        swraw[tid]     = log1pf(expf(w_sp_d[r * 2 + cc]));
        swraw[9 + tid] = log1pf(expf(w_sp_s[r * 2 + cc]));
    }
    if (tid == 9)  sw[18] = 1.f / (1.f + expf(-w_prop_s[0]));   // wps
    if (tid == 10) sw[19] = log1pf(expf(w_pow_s[0]));           // wpow
    if (tid < 9) {   // same-wave: raw writes complete (lockstep) before reads
        float sum_d = 0.f, sum_s = 0.f;
        #pragma unroll
        for (int k = 0; k < 9; ++k) { sum_d += swraw[k]; sum_s += swraw[9 + k]; }
        sw[tid]     = swraw[tid]     / sum_d;
        sw[9 + tid] = swraw[9 + tid] / sum_s;
    }

    // ---- Phase A: vectorized load at halo-3 (30 rows x 10 float4 segs) ----
    for (int it = tid; it < R3Y * 10; it += 256) {   // 300 items
        int row = it / 10, seg = it - row * 10;
        int gy = ty0 - 3 + row;
        int gxb = tx0 - 4 + seg * 4;
        float4 vd4 = make_float4(0.f, 0.f, 0.f, 0.f);
        float4 vc4 = vd4;
        if ((unsigned)gy < (unsigned)Hh) {
            bool safe = (seg > 0 && seg < 9) || (seg == 0 ? (tx0 > 0) : (tx0 + TSX < Ww));
            if (safe) {
                vd4 = *(const float4*)(dcd + gy * Ww + gxb);
                vc4 = *(const float4*)(cd  + gy * Ww + gxb);
            } else {
                if ((unsigned)(gxb + 0) < (unsigned)Ww) { vd4.x = dcd[gy*Ww+gxb+0]; vc4.x = cd[gy*Ww+gxb+0]; }
                if ((unsigned)(gxb + 1) < (unsigned)Ww) { vd4.y = dcd[gy*Ww+gxb+1]; vc4.y = cd[gy*Ww+gxb+1]; }
                if ((unsigned)(gxb + 2) < (unsigned)Ww) { vd4.z = dcd[gy*Ww+gxb+2]; vc4.z = cd[gy*Ww+gxb+2]; }
                if ((unsigned)(gxb + 3) < (unsigned)Ww) { vd4.w = dcd[gy*Ww+gxb+3]; vc4.w = cd[gy*Ww+gxb+3]; }
            }
        }
        int lxb = seg * 4 - 1;   // lx of component 0
        if ((unsigned)(lxb + 0) < (unsigned)R3X) s_qc[row][lxb + 0] = make_float2(vd4.x / (vc4.x + EPSF), vc4.x);
        if ((unsigned)(lxb + 1) < (unsigned)R3X) s_qc[row][lxb + 1] = make_float2(vd4.y / (vc4.y + EPSF), vc4.y);
        if ((unsigned)(lxb + 2) < (unsigned)R3X) s_qc[row][lxb + 2] = make_float2(vd4.z / (vc4.z + EPSF), vc4.z);
        if ((unsigned)(lxb + 3) < (unsigned)R3X) s_qc[row][lxb + 3] = make_float2(vd4.w / (vc4.w + EPSF), vc4.w);
    }

    // ---- Prefetch cs/scs for Phase B (36 cols x 7 groups of 4 rows) ----
    const int xB = tid % R2X;          // 0..35
    const int tyB = tid / R2X;         // active < 7 (252 threads)
    const int yb0 = tyB * 4;
    float pcs[4], pscs[4];
    if (tyB < 7) {
        int gx = tx0 - 2 + xB;
        bool colok = (unsigned)gx < (unsigned)Ww;
        #pragma unroll
        for (int j = 0; j < 4; ++j) {
            int gy = ty0 - 2 + yb0 + j;
            bool ok = colok && (unsigned)gy < (unsigned)Hh;
            int idx = ok ? (b * PLANE + gy * Ww + gx) : 0;
            pcs[j]  = ok ? cs[idx]  : 0.f;
            pscs[j] = ok ? scs[idx] : 0.f;
        }
    }
    __syncthreads();

    const float wps  = sw[18];
    const float wpow = sw[19];
    const float onemw = 1.f - wps;

    // ---- Phase B: stage 1, column sweep. Hierarchical first-wins argmax:
    // row-max over dx (k-minor) then combine over dy (k-major) — exactly
    // reproduces jnp.argmax first-occurrence order.
    if (tyB < 7) {
        float ma[3], md[3], mc[3];    // jmax row-partials (key, dq, c)
        float nv[3], nq[3];           // jmin row-partials (vc, dq+eps)
#define HROW_B(rr, slot) { \
        float2 q0 = s_qc[rr][xB]; float2 q1 = s_qc[rr][xB + 1]; float2 q2 = s_qc[rr][xB + 2]; \
        float a0 = q0.x * q0.y, a1 = q1.x * q1.y, a2 = q2.x * q2.y; \
        float A = a0, D = q0.x, C = q0.y; \
        if (a1 > A) { A = a1; D = q1.x; C = q1.y; } \
        if (a2 > A) { A = a2; D = q2.x; C = q2.y; } \
        ma[slot] = A; md[slot] = D; mc[slot] = C; \
        float V = q0.y, Q = q0.x + EPSF; \
        float e1 = q1.x + EPSF, e2 = q2.x + EPSF; \
        if (q1.y * Q > V * e1) { V = q1.y; Q = e1; } \
        if (q2.y * Q > V * e2) { V = q2.y; Q = e2; } \
        nv[slot] = V; nq[slot] = Q; }
        HROW_B(yb0 + 0, 0)
        HROW_B(yb0 + 1, 1)
        #pragma unroll
        for (int j = 0; j < 4; ++j) {
            const int sl2 = (j + 2) % 3, s0 = j % 3, s1 = (j + 1) % 3;
            HROW_B(yb0 + j + 2, sl2)
            float A = ma[s0], D = md[s0], C = mc[s0];
            if (ma[s1]  > A) { A = ma[s1];  D = md[s1];  C = mc[s1];  }
            if (ma[sl2] > A) { A = ma[sl2]; D = md[sl2]; C = mc[sl2]; }
            float V = nv[s0], Q = nq[s0];
            if (nv[s1]  * Q > V * nq[s1])  { V = nv[s1];  Q = nq[s1];  }
            if (nv[sl2] * Q > V * nq[sl2]) { V = nv[sl2]; Q = nq[sl2]; }
            const int yb = yb0 + j;
            const int gy = ty0 - 2 + yb, gx = tx0 - 2 + xB;
            float tc = 0.f, ts = 0.f;
            if ((unsigned)gy < (unsigned)Hh && (unsigned)gx < (unsigned)Ww) {
                float s_new = __builtin_amdgcn_exp2f(wpow *
                    (__builtin_amdgcn_logf(Q) - __builtin_amdgcn_logf(D + EPSF)));
                float cs_new = C * V;
                tc = pcs[j]  * wps + cs_new * onemw;
                ts = pscs[j] * wps + s_new * cs_new * onemw;
            }
            s_t[yb][xB] = make_float2(tc, ts);
        }
    }
    __syncthreads();

    // ---- Phase C: stage 2 conv, column sweep (34 cols x 7 groups of 4) ----
    // Results kept in registers; re-staged into dead s_t for aligned D writes.
    const int xC = tid % R1X;          // 0..33
    const int tyC = tid / R1X;         // active < 7 (238 threads)
    const int yc0 = tyC * 4;
    float2 cres[4];
    if (tyC < 7) {
        const float wa0 = sw[9],  wb0 = sw[10];
        const float wa1 = sw[12], wb1 = sw[13];
        const float wa2 = sw[15], wb2 = sw[16];
        float2 u[3], tm[3];
#define HROW_C(rr, slot) { \
        float2 t0 = s_t[rr][xC]; float2 t1 = s_t[rr][xC + 1]; float2 t2 = s_t[rr][xC + 2]; \
        u[slot] = make_float2(t0.x + t2.x, t0.y + t2.y); tm[slot] = t1; }
        HROW_C(yc0 + 0, 0)
        HROW_C(yc0 + 1, 1)
        #pragma unroll
        for (int j = 0; j < 4; ++j) {
            const int yc = yc0 + j;
            if (yc < R1Y) {
                const int sl2 = (j + 2) % 3, s0 = j % 3, s1 = (j + 1) % 3;
                HROW_C(yc + 2, sl2)
                float accC = wa0 * u[s0].x + wb0 * tm[s0].x
                           + wa1 * u[s1].x + wb1 * tm[s1].x
                           + wa2 * u[sl2].x + wb2 * tm[sl2].x;
                float accS = wa0 * u[s0].y + wb0 * tm[s0].y
                           + wa1 * u[s1].y + wb1 * tm[s1].y
                           + wa2 * u[sl2].y + wb2 * tm[sl2].y;
                const int gy = ty0 - 1 + yc, gx = tx0 - 1 + xC;
                bool in_img = (unsigned)gy < (unsigned)Hh && (unsigned)gx < (unsigned)Ww;
                s_s[yc][xC] = __float2half(
                    in_img ? (accS * __builtin_amdgcn_rcpf(accC + EPSF)) : 0.f);
                cres[j] = make_float2(accC, accS);
            }
        }
    }
    __syncthreads();   // all s_t reads done; s_s ready

    // ---- Phase C2: dump conv results into dead s_t for aligned writes ----
    if (tyC < 7) {
        #pragma unroll
        for (int j = 0; j < 4; ++j) {
            const int yc = yc0 + j;
            if (yc < R1Y) s_t[yc][xC] = cres[j];
        }
    }
    __syncthreads();

    // ---- Phase D: stage 3 + ALL global writes (32 cols x 8 groups of 3) ----
    {
        const int xD = tid & 31, tyD = tid >> 5;
        const int yd0 = tyD * 3;
        float wdk[9];
        #pragma unroll
        for (int k = 0; k < 9; ++k) wdk[k] = sw[k];
        float  srw[3][3];
        float2 qrw[3][3];
#define HROW_D(rr, slot) { \
        srw[slot][0] = __half2float(s_s[rr][xD]); \
        srw[slot][1] = __half2float(s_s[rr][xD + 1]); \
        srw[slot][2] = __half2float(s_s[rr][xD + 2]); \
        qrw[slot][0] = s_qc[rr + 2][xD + 2]; qrw[slot][1] = s_qc[rr + 2][xD + 3]; qrw[slot][2] = s_qc[rr + 2][xD + 4]; }
        HROW_D(yd0 + 0, 0)
        HROW_D(yd0 + 1, 1)
#define TAP_D(slot, kk, cc2) { \
        float wsk = ((kk) == 4) ? 1.f : (srw[slot][cc2] * sc); \
        float w = wdk[kk] * wsk; \
        float2 q = qrw[slot][cc2]; \
        acc_d += w * (q.x * (q.y + EPSF)); \
        acc_c += w * q.y; \
        acc_w += w; }
        #pragma unroll
        for (int j = 0; j < 3; ++j) {
            const int sl2 = (j + 2) % 3, s0 = j % 3, s1 = (j + 1) % 3;
            HROW_D(yd0 + j + 2, sl2)
            float sc = srw[s1][1];
            float acc_d = 0.f, acc_c = 0.f, acc_w = 0.f;
            TAP_D(s0, 0, 0) TAP_D(s0, 1, 1) TAP_D(s0, 2, 2)
            TAP_D(s1, 3, 0) TAP_D(s1, 4, 1) TAP_D(s1, 5, 2)
            TAP_D(sl2, 6, 0) TAP_D(sl2, 7, 1) TAP_D(sl2, 8, 2)
            float rinv = __builtin_amdgcn_rcpf(acc_w + EPSF);
            const int iy = yd0 + j;
            int idx = (ty0 + iy) * Ww + (tx0 + xD);
            float2 cv = s_t[iy + 1][xD + 1];   // (accC, accS) for this pixel
            out[(2 * b)     * PLANE + idx] = acc_d * rinv;   // x_out d-part
            out[(2 * b + 1) * PLANE + idx] = acc_c * rinv;   // x_out c-part
            out[(8 + b)     * PLANE + idx] = cv.y;           // scs_out
            out[(12 + b)    * PLANE + idx] = cv.x;           // cs_out
        }
    }
}

extern "C" void kernel_launch(void* const* d_in, const int* in_sizes, int n_in,
                              void* d_out, int out_size, void* d_ws, size_t ws_size,
                              hipStream_t stream) {
    const float* x        = (const float*)d_in[0];
    const float* scs      = (const float*)d_in[1];
    const float* cs       = (const float*)d_in[2];
    // d_in[3] = w_channel_d (1,1) -> normalizes to 1, unused
    const float* w_sp_d   = (const float*)d_in[4];
    const float* w_pow_s  = (const float*)d_in[5];
    const float* w_prop_s = (const float*)d_in[6];
    // d_in[7] = w_channel_s (1,1) -> normalizes to 1, unused
    const float* w_sp_s   = (const float*)d_in[8];
    float* out  = (float*)d_out;

    fused_all<<<dim3(24 * 32 * Bb), 256, 0, stream>>>(x, scs, cs, w_sp_d, w_sp_s,
                                                      w_pow_s, w_prop_s, out);
}